// Round 2
// baseline (390.789 us; speedup 1.0000x reference)
//
#include <hip/hip_runtime.h>
#include <hip/hip_bf16.h>
#include <stdint.h>

// ---------------------------------------------------------------------------
// VarianceAdaptor. Round 5: fuse conv1+conv2 into ONE kernel with h1 kept in
// LDS (XOR-swizzled 160x256 bf16 tile). Eliminates the 96MB h1b HBM
// round-trip, the 25M scalar bf16 stores, and one dispatch. Each block:
// conv1 over 160 rows (16-row halo each side, recomputed) -> LN -> h1 in LDS
// -> conv2 over 128 rows reading A-fragments from LDS (B weights
// double-buffered) -> LN -> linear head -> 171-row length-regulator tail.
// 768 blocks, 512 threads (8 waves: rh in {0,1} x c4 in {0..3}), 139KB LDS,
// 1 block/CU, exactly 3 scheduling rounds.
// ---------------------------------------------------------------------------

typedef __bf16 bf16;
typedef __attribute__((ext_vector_type(8))) __bf16 bf16x8;
typedef __attribute__((ext_vector_type(4))) float f32x4;

#define TSEQ 1024

// output chunk offsets (floats)
#define O1 33554432          // pitch_pred
#define O2 33587200          // energy_pred
#define O3 33619968          // log_dur
#define O4 33652736          // duration passthrough
#define O5 33685504          // mel_len
#define O6 33685536          // mel_mask
#define OUT_END_B 135266432  // (O6 + 131072) * 4

// scratch sizes (bytes)
#define XB_SZ 16777216
#define WT_SZ 393216
#define WT_TOT (6 * WT_SZ)
#define SCRATCH_SZ (XB_SZ + WT_TOT)

// ws byte offsets
#define CUM_OFF 0
#define ADDROW_OFF 131072
#define ZEROS_OFF 262144
#define WS_SCR_OFF 524288
#define WS_NEED ((size_t)WS_SCR_OFF + (size_t)SCRATCH_SZ)

// legacy d_out scratch base (fallback path only)
#define XB_OFF 512

#define LR_PER_BLK 171       // 768 * 171 = 131328 >= 131072

// ---------------------------------------------------------------------------
// Fused prep: [0,4096) cvt_x | [4096,4672) cvt_w | [4672,4800) bins+zpage |
// [4800,4832) scan. All independent; consumed by later dispatches.
__global__ __launch_bounds__(256) void k_prep(
    const float* __restrict__ x, bf16* __restrict__ xb,
    const float* __restrict__ w1, const float* __restrict__ w2,
    bf16* __restrict__ wt,
    const float* __restrict__ pt, const float* __restrict__ et,
    const float* __restrict__ pbins, const float* __restrict__ ebins,
    int* __restrict__ addrow, float* __restrict__ zpage,
    const int* __restrict__ dur, const int* __restrict__ maxlen,
    float* __restrict__ out, int* __restrict__ cum) {
  int bid = blockIdx.x;
  int tid = threadIdx.x;
  if (bid < 4096) {
    // fp32 -> bf16 copy of x (plain row-major, 256 ch/row)
    int t = bid * 256 + tid;
    int g = t >> 5;
    int u = t & 31;
    const float4* s = (const float4*)(x + ((size_t)g << 8) + (u << 3));
    float4 a = s[0], b = s[1];
    bf16x8 o;
    o[0] = (bf16)a.x; o[1] = (bf16)a.y; o[2] = (bf16)a.z; o[3] = (bf16)a.w;
    o[4] = (bf16)b.x; o[5] = (bf16)b.y; o[6] = (bf16)b.z; o[7] = (bf16)b.w;
    *(bf16x8*)(xb + ((size_t)g << 8) + (u << 3)) = o;
  } else if (bid < 4672) {
    // (3,K,H,F) WIO fp32 -> wT[m][f][k] bf16 (k = dt*256 + c)
    int bw = bid - 4096;
    int m = bw / 96;
    int r = bw % 96;
    int f = (r & 3) * 64 + (tid & 63);
    int u = (r >> 2) * 4 + (tid >> 6);
    const float* W = (m < 3) ? w1 : w2;
    int i = (m < 3) ? m : m - 3;
    int dt = u >> 5;
    int c0 = (u & 31) << 3;
    const float* src = W + (((size_t)(i * 3 + dt) * 256 + c0) << 8) + f;
    bf16x8 o;
#pragma unroll
    for (int cc = 0; cc < 8; ++cc) o[cc] = (bf16)src[(size_t)cc << 8];
    *(bf16x8*)(wt + (size_t)m * 196608 + (size_t)f * 768 + (u << 3)) = o;
  } else if (bid < 4800) {
    // searchsorted(left) of pitch/energy targets into bins; zero the zpage
    __shared__ float pb[255], eb[255];
    if (tid < 255) { pb[tid] = pbins[tid]; eb[tid] = ebins[tid]; }
    if (bid == 4672 && tid < 64) zpage[tid] = 0.f;
    __syncthreads();
    int g = (bid - 4672) * 256 + tid;
    float pv = pt[g], ev = et[g];
    int lo = 0, hi = 255;
    while (lo < hi) { int md = (lo + hi) >> 1; if (pb[md] < pv) lo = md + 1; else hi = md; }
    int pi = lo;
    lo = 0; hi = 255;
    while (lo < hi) { int md = (lo + hi) >> 1; if (eb[md] < ev) lo = md + 1; else hi = md; }
    addrow[g] = pi | (lo << 16);
  } else {
    // cumsum(dur) + mel_len + duration passthrough
    __shared__ int lds[256];
    int b = bid - 4800;
    int4 d = ((const int4*)(dur + b * 1024))[tid];
    int p0 = d.x, p1 = p0 + d.y, p2 = p1 + d.z, p3 = p2 + d.w;
    int val = p3;
    lds[tid] = val;
    __syncthreads();
    for (int off = 1; off < 256; off <<= 1) {
      int t = (tid >= off) ? lds[tid - off] : 0;
      __syncthreads();
      val += t;
      lds[tid] = val;
      __syncthreads();
    }
    int excl = val - p3;
    int4 c;
    c.x = excl + p0; c.y = excl + p1; c.z = excl + p2; c.w = excl + p3;
    ((int4*)(cum + b * 1024))[tid] = c;
    float4 fd;
    fd.x = (float)d.x; fd.y = (float)d.y; fd.z = (float)d.z; fd.w = (float)d.w;
    ((float4*)(out + O4 + b * 1024))[tid] = fd;
    if (tid == 255) {
      int mel = val < maxlen[0] ? val : maxlen[0];
      out[O5 + b] = (float)mel;
    }
  }
}

// ---------------------------------------------------------------------------
// Fused conv1 + conv2 + head + LR tail. bid in [0,768): y = bid>>8,
// g0 = (bid&255)*128. 512 threads = 8 waves (rh = wv>>2, c4 = wv&3).
// conv1: 160x256 (rows g0-16 .. g0+144), wave tile 80x64 (acc[5][4]).
// conv2: 128x256 output rows, wave tile 64x64 (acc[4][4]); A from H1 LDS.
__global__ __launch_bounds__(512, 2) void k_fused(
    const bf16* __restrict__ xb, const bf16* __restrict__ wt,
    const float* __restrict__ b1, const float* __restrict__ g1,
    const float* __restrict__ be1, const float* __restrict__ b2,
    const float* __restrict__ g2, const float* __restrict__ be2,
    const float* __restrict__ lw0, const float* __restrict__ lb0,
    const unsigned char* __restrict__ mask, float* __restrict__ outb,
    const char* __restrict__ zpage,
    const float* __restrict__ xf, const int* __restrict__ cum,
    const int* __restrict__ addrow, const float* __restrict__ pemb,
    const float* __restrict__ eemb, const int* __restrict__ maxlen,
    int lrn) {
  __shared__ __align__(16) char Abuf[2][10240];   // 160 rows x 64B, dbuf
  __shared__ __align__(16) char Bbuf[2][16384];   // 256 f x 64B, dbuf
  __shared__ __align__(16) char H1[160 * 512];    // h1, XOR-swizzled rows
  __shared__ float redS[160][4];
  __shared__ float redS2[160][4];
  __shared__ float predr[128][4];

  const int tid = threadIdx.x;
  const int bid = blockIdx.x;
  const int wv = tid >> 6;
  const int ln = tid & 63;
  const int q = ln >> 4;
  const int m16 = ln & 15;
  const int rh = wv >> 2;        // 0..1
  const int c4 = wv & 3;         // 0..3
  const int y = bid >> 8;
  const int g0 = (bid & 255) << 7;
  const int t0 = g0 & (TSEQ - 1);

  const bf16* W1 = wt + (size_t)y * 196608;
  const bf16* W2 = wt + (size_t)(3 + y) * 196608;

  // staging lane geometry: slot s = tid covers (row = s>>2, slot = s&3);
  // content at physical slot p is source chunk p ^ ((row>>1)&3).
  const int arow = tid >> 2;     // 0..127 (second inst adds 128 rows)
  const int asl = tid & 3;
  const int perm = asl ^ ((arow >> 1) & 3);   // same for row+128 / f+128

// conv1 staging: A rows [g0-16+arow(+128)] at k-chunk kb, plus B chunk.
#define STAGE1(KB, BUF)                                                        \
  {                                                                            \
    const int dt_ = (KB) >> 3;                                                 \
    const int c0_ = ((KB)&7) << 5;                                             \
    {                                                                          \
      int tr_ = t0 - 17 + arow + dt_;                                          \
      const char* src_ = ((unsigned)tr_ < 1024u)                               \
          ? (const char*)(xb + ((size_t)(g0 - 17 + arow + dt_) << 8) + c0_ +   \
                          perm * 8)                                            \
          : zpage + asl * 16;                                                  \
      __builtin_amdgcn_global_load_lds(                                        \
          (const __attribute__((address_space(1))) void*)src_,                 \
          (__attribute__((address_space(3))) void*)(Abuf[BUF] + tid * 16),     \
          16, 0, 0);                                                           \
    }                                                                          \
    if (tid < 128) {                                                           \
      int tr_ = t0 + 111 + arow + dt_;                                         \
      const char* src_ = ((unsigned)tr_ < 1024u)                               \
          ? (const char*)(xb + ((size_t)(g0 + 111 + arow + dt_) << 8) + c0_ +  \
                          perm * 8)                                            \
          : zpage + asl * 16;                                                  \
      __builtin_amdgcn_global_load_lds(                                        \
          (const __attribute__((address_space(1))) void*)src_,                 \
          (__attribute__((address_space(3))) void*)(Abuf[BUF] + 8192 +         \
                                                    tid * 16),                 \
          16, 0, 0);                                                           \
    }                                                                          \
    STAGEB(W1, KB, BUF)                                                        \
  }

#define STAGEB(WP, KB, BUF)                                                    \
  {                                                                            \
    const bf16* s0_ = (WP) + (size_t)arow * 768 + (KB)*32 + perm * 8;          \
    __builtin_amdgcn_global_load_lds(                                          \
        (const __attribute__((address_space(1))) void*)s0_,                    \
        (__attribute__((address_space(3))) void*)(Bbuf[BUF] + tid * 16),       \
        16, 0, 0);                                                             \
    __builtin_amdgcn_global_load_lds(                                          \
        (const __attribute__((address_space(1))) void*)(s0_ + 98304),          \
        (__attribute__((address_space(3))) void*)(Bbuf[BUF] + 8192 +           \
                                                  tid * 16),                   \
        16, 0, 0);                                                             \
  }

  const int spq = (q ^ ((m16 >> 1) & 3)) << 4;       // fragment slot bytes
  const int aoff = (rh * 80 + m16) * 64 + spq;       // + mi*1024
  const int boff = (c4 * 64 + m16) * 64 + spq;       // + ni*1024

  // ---------------- conv1: 160 x 256, K = 768 ----------------
  f32x4 acc[5][4];
#pragma unroll
  for (int a = 0; a < 5; a++)
#pragma unroll
    for (int b = 0; b < 4; b++) acc[a][b] = (f32x4){0.f, 0.f, 0.f, 0.f};

  STAGE1(0, 0);
#pragma unroll 2
  for (int kb = 0; kb < 24; ++kb) {
    int buf = kb & 1;
    __syncthreads();
    if (kb < 23) STAGE1(kb + 1, buf ^ 1);
    bf16x8 af[5], bfr[4];
#pragma unroll
    for (int mi = 0; mi < 5; ++mi)
      af[mi] = *(const bf16x8*)(Abuf[buf] + aoff + mi * 1024);
#pragma unroll
    for (int ni = 0; ni < 4; ++ni)
      bfr[ni] = *(const bf16x8*)(Bbuf[buf] + boff + ni * 1024);
#pragma unroll
    for (int mi = 0; mi < 5; ++mi)
#pragma unroll
      for (int ni = 0; ni < 4; ++ni)
        acc[mi][ni] = __builtin_amdgcn_mfma_f32_16x16x32_bf16(
            af[mi], bfr[ni], acc[mi][ni], 0, 0, 0);
  }

  // bias + ReLU + LN stats for 160 rows
  {
    const float* bias = b1 + y * 256;
    const float* gamma = g1 + y * 256;
    const float* beta = be1 + y * 256;
    float bias_v[4], g_v[4], be_v[4];
#pragma unroll
    for (int ni = 0; ni < 4; ni++) {
      int nf = (c4 << 6) + (ni << 4) + m16;
      bias_v[ni] = bias[nf];
      g_v[ni] = gamma[nf];
      be_v[ni] = beta[nf];
    }
#pragma unroll
    for (int mi = 0; mi < 5; mi++) {
#pragma unroll
      for (int r = 0; r < 4; r++) {
        float s1 = 0.f, s2 = 0.f;
#pragma unroll
        for (int ni = 0; ni < 4; ni++) {
          float v = acc[mi][ni][r] + bias_v[ni];
          v = fmaxf(v, 0.f);
          acc[mi][ni][r] = v;
          s1 += v;
          s2 += v * v;
        }
#pragma unroll
        for (int d = 1; d < 16; d <<= 1) {
          s1 += __shfl_xor(s1, d);
          s2 += __shfl_xor(s2, d);
        }
        if (m16 == 0) {
          int m = rh * 80 + (mi << 4) + (q << 2) + r;
          redS[m][c4] = s1;
          redS2[m][c4] = s2;
        }
      }
    }
    __syncthreads();
    // normalize + write h1 into swizzled LDS (zero rows outside the batch)
#pragma unroll
    for (int mi = 0; mi < 5; mi++) {
#pragma unroll
      for (int r = 0; r < 4; r++) {
        int m = rh * 80 + (mi << 4) + (q << 2) + r;
        float mu = (redS[m][0] + redS[m][1] + redS[m][2] + redS[m][3]) *
                   0.00390625f;
        float var = (redS2[m][0] + redS2[m][1] + redS2[m][2] + redS2[m][3]) *
                        0.00390625f - mu * mu;
        float rs = rsqrtf(var + 1e-5f);
        int trow = t0 - 16 + m;
        bool vr = (unsigned)trow < 1024u;
#pragma unroll
        for (int ni = 0; ni < 4; ni++) {
          float v = vr ? (acc[mi][ni][r] - mu) * rs * g_v[ni] + be_v[ni] : 0.f;
          int c = (c4 << 6) + (ni << 4) + m16;
          *(bf16*)(H1 + m * 512 + ((c * 2) ^ ((m & 7) << 4))) = (bf16)v;
        }
      }
    }
  }

  // ---------------- conv2: 128 x 256, K = 768, A from H1 ----------------
  f32x4 acc2[4][4];
#pragma unroll
  for (int a = 0; a < 4; a++)
#pragma unroll
    for (int b = 0; b < 4; b++) acc2[a][b] = (f32x4){0.f, 0.f, 0.f, 0.f};

  STAGEB(W2, 0, 0);
#pragma unroll 2
  for (int kb = 0; kb < 24; ++kb) {
    int buf = kb & 1;
    __syncthreads();   // drains STAGEB(kb); first iter also fences H1 writes
    if (kb < 23) STAGEB(W2, kb + 1, buf ^ 1);
    int dt = kb >> 3;
    int cbyte = ((kb & 7) << 6) + (q << 4);   // byte offset of lane's k-chunk
    int hbase = 15 + rh * 64 + dt + m16;
    bf16x8 af[4], bfr[4];
#pragma unroll
    for (int mi = 0; mi < 4; ++mi) {
      int hr = hbase + (mi << 4);
      af[mi] = *(const bf16x8*)(H1 + hr * 512 + (cbyte ^ ((hr & 7) << 4)));
    }
#pragma unroll
    for (int ni = 0; ni < 4; ++ni)
      bfr[ni] = *(const bf16x8*)(Bbuf[buf] + boff + ni * 1024);
#pragma unroll
    for (int mi = 0; mi < 4; ++mi)
#pragma unroll
      for (int ni = 0; ni < 4; ++ni)
        acc2[mi][ni] = __builtin_amdgcn_mfma_f32_16x16x32_bf16(
            af[mi], bfr[ni], acc2[mi][ni], 0, 0, 0);
  }

  // bias + ReLU + LN + linear head for 128 output rows
  {
    const float* bias = b2 + y * 256;
    const float* gamma = g2 + y * 256;
    const float* beta = be2 + y * 256;
    const float* lw = lw0 + y * 256;
    float bias_v[4], g_v[4], be_v[4], lw_v[4];
#pragma unroll
    for (int ni = 0; ni < 4; ni++) {
      int nf = (c4 << 6) + (ni << 4) + m16;
      bias_v[ni] = bias[nf];
      g_v[ni] = gamma[nf];
      be_v[ni] = beta[nf];
      lw_v[ni] = lw[nf];
    }
#pragma unroll
    for (int mi = 0; mi < 4; mi++) {
#pragma unroll
      for (int r = 0; r < 4; r++) {
        float s1 = 0.f, s2 = 0.f;
#pragma unroll
        for (int ni = 0; ni < 4; ni++) {
          float v = acc2[mi][ni][r] + bias_v[ni];
          v = fmaxf(v, 0.f);
          acc2[mi][ni][r] = v;
          s1 += v;
          s2 += v * v;
        }
#pragma unroll
        for (int d = 1; d < 16; d <<= 1) {
          s1 += __shfl_xor(s1, d);
          s2 += __shfl_xor(s2, d);
        }
        if (m16 == 0) {
          int m = (rh << 6) + (mi << 4) + (q << 2) + r;
          redS[m][c4] = s1;
          redS2[m][c4] = s2;
        }
      }
    }
    __syncthreads();
#pragma unroll
    for (int mi = 0; mi < 4; mi++) {
#pragma unroll
      for (int r = 0; r < 4; r++) {
        int m = (rh << 6) + (mi << 4) + (q << 2) + r;
        float mu = (redS[m][0] + redS[m][1] + redS[m][2] + redS[m][3]) *
                   0.00390625f;
        float var = (redS2[m][0] + redS2[m][1] + redS2[m][2] + redS2[m][3]) *
                        0.00390625f - mu * mu;
        float rs = rsqrtf(var + 1e-5f);
        float p = 0.f;
#pragma unroll
        for (int ni = 0; ni < 4; ni++) {
          float v = (acc2[mi][ni][r] - mu) * rs * g_v[ni] + be_v[ni];
          p += v * lw_v[ni];
        }
#pragma unroll
        for (int d = 1; d < 16; d <<= 1) p += __shfl_xor(p, d);
        if (m16 == 0) predr[m][c4] = p;
      }
    }
    __syncthreads();
    if (tid < 128) {
      int gg = g0 + tid;
      float p = predr[tid][0] + predr[tid][1] + predr[tid][2] + predr[tid][3] +
                lb0[y];
      if (mask[gg]) p = 0.f;
      float* pd = outb + (y == 0 ? O3 : (y == 1 ? O1 : O2));
      pd[gg] = p;
    }
  }

  // ---------------- length-regulator tail (memory-bound) ----------------
  if (lrn) {
    int rid0 = bid * lrn;
    int ml = maxlen[0];
    for (int j = wv; j < lrn; j += 8) {
      int rid = rid0 + j;
      if (rid >= 131072) break;
      int b = rid >> 12;
      int jj = rid & 4095;
      const int* cb = cum + (b << 10);
      int c1 = cb[ln * 16 + 15];           // segment maxima (level-1 search)
      int total = __shfl(c1, 63);
      int mel = total < ml ? total : ml;
      bool valid = jj < mel;
      float4 res = {0.f, 0.f, 0.f, 0.f};
      if (valid) {
        unsigned long long m1 = __ballot(jj < c1);
        int s = __ffsll(m1) - 1;
        unsigned long long m2 = __ballot(jj < cb[s * 16 + (ln & 15)]);
        int p = __ffsll(m2) - 1;
        int i = s * 16 + p;
        int ar = addrow[(b << 10) + i];
        int pi = ar & 0xffff, ei = ar >> 16;
        const float4* xr = (const float4*)(xf + (((size_t)(b << 10) + i) << 8));
        const float4* pr = (const float4*)(pemb + ((size_t)pi << 8));
        const float4* er = (const float4*)(eemb + ((size_t)ei << 8));
        float4 a = xr[ln], pp = pr[ln], e = er[ln];
        res.x = a.x + pp.x + e.x;
        res.y = a.y + pp.y + e.y;
        res.z = a.z + pp.z + e.z;
        res.w = a.w + pp.w + e.w;
      }
      ((float4*)(outb + ((size_t)rid << 8)))[ln] = res;
      if (ln == 0) outb[O6 + rid] = valid ? 0.f : 1.f;
    }
  }
}
#undef STAGE1
#undef STAGEB

// ---------------------------------------------------------------------------
// Standalone length regulation (fallback path only). 16 rows/block;
// grid MUST be 8192 to cover all 32*4096 output rows.
__global__ __launch_bounds__(256) void k_lr(const float* __restrict__ x,
                                            const int* __restrict__ cum,
                                            const int* __restrict__ addrow,
                                            const float* __restrict__ pemb,
                                            const float* __restrict__ eemb,
                                            const int* __restrict__ maxlen,
                                            float* __restrict__ outb) {
  __shared__ int cl[1024];
  int tid = threadIdx.x;
  int rid0 = blockIdx.x << 4;
  int b = rid0 >> 12;
  ((int4*)cl)[tid] = ((const int4*)(cum + (b << 10)))[tid];
  __syncthreads();
  int lane = tid & 63;
  int wv = tid >> 6;
  int total = cl[1023];
  int ml = maxlen[0];
  int mel = total < ml ? total : ml;
  int c1 = cl[lane * 16 + 15];
#pragma unroll
  for (int rr = 0; rr < 4; ++rr) {
    int rid = rid0 + (wv << 2) + rr;
    int j = rid & 4095;
    bool valid = j < mel;
    float4 res = {0.f, 0.f, 0.f, 0.f};
    if (valid) {
      unsigned long long m1 = __ballot(j < c1);
      int s = __ffsll(m1) - 1;
      unsigned long long m2 = __ballot(j < cl[s * 16 + (lane & 15)]);
      int p = __ffsll(m2) - 1;
      int i = s * 16 + p;
      int ar = addrow[(b << 10) + i];
      int pi = ar & 0xffff, ei = ar >> 16;
      const float4* xr = (const float4*)(x + (((size_t)(b << 10) + i) << 8));
      const float4* pr = (const float4*)(pemb + ((size_t)pi << 8));
      const float4* er = (const float4*)(eemb + ((size_t)ei << 8));
      float4 a = xr[lane], pp = pr[lane], e = er[lane];
      res.x = a.x + pp.x + e.x;
      res.y = a.y + pp.y + e.y;
      res.z = a.z + pp.z + e.z;
      res.w = a.w + pp.w + e.w;
    }
    ((float4*)(outb + ((size_t)rid << 8)))[lane] = res;
    if (lane == 0) outb[O6 + rid] = valid ? 0.f : 1.f;
  }
}

// ---------------------------------------------------------------------------
extern "C" void kernel_launch(void* const* d_in, const int* in_sizes, int n_in,
                              void* d_out, int out_size, void* d_ws, size_t ws_size,
                              hipStream_t stream) {
  const float* x = (const float*)d_in[0];
  const unsigned char* src_mask = (const unsigned char*)d_in[1];
  const int* dur = (const int*)d_in[2];
  const float* pt = (const float*)d_in[3];
  const float* et = (const float*)d_in[4];
  const int* maxlen = (const int*)d_in[5];
  const float* w1 = (const float*)d_in[6];
  const float* b1 = (const float*)d_in[7];
  const float* g1 = (const float*)d_in[8];
  const float* be1 = (const float*)d_in[9];
  const float* w2 = (const float*)d_in[10];
  const float* b2 = (const float*)d_in[11];
  const float* g2 = (const float*)d_in[12];
  const float* be2 = (const float*)d_in[13];
  const float* lw = (const float*)d_in[14];
  const float* lb = (const float*)d_in[15];
  const float* pbins = (const float*)d_in[16];
  const float* pemb = (const float*)d_in[17];
  const float* ebins = (const float*)d_in[18];
  const float* eemb = (const float*)d_in[19];

  float* outf = (float*)d_out;
  char* ob = (char*)d_out;
  int* cum = (int*)((char*)d_ws + CUM_OFF);
  int* addrow = (int*)((char*)d_ws + ADDROW_OFF);
  float* zpage = (float*)((char*)d_ws + ZEROS_OFF);

  // Scratch placement: prefer ws, then d_out tail beyond real outputs,
  // else legacy overlapped layout (requires separate final k_lr dispatch,
  // since scratch then aliases the LR output region).
  int merged = 0;
  char* sb = nullptr;
  if (ws_size >= WS_NEED) {
    sb = (char*)d_ws + WS_SCR_OFF;
    merged = 1;
  } else if ((size_t)out_size >= (size_t)OUT_END_B + (size_t)SCRATCH_SZ) {
    sb = ob + OUT_END_B;
    merged = 1;
  } else {
    sb = ob + XB_OFF;
  }
  bf16* xb = (bf16*)sb;
  bf16* wt = (bf16*)(sb + XB_SZ);

  hipLaunchKernelGGL(k_prep, dim3(4832), dim3(256), 0, stream,
                     x, xb, w1, w2, wt, pt, et, pbins, ebins, addrow, zpage,
                     dur, maxlen, outf, cum);
  hipLaunchKernelGGL(k_fused, dim3(768), dim3(512), 0, stream,
                     xb, wt, b1, g1, be1, b2, g2, be2, lw, lb, src_mask, outf,
                     (const char*)zpage, x, cum, addrow, pemb, eemb, maxlen,
                     merged ? LR_PER_BLK : 0);
  if (!merged) {
    hipLaunchKernelGGL(k_lr, dim3(8192), dim3(256), 0, stream, x, cum, addrow,
                       pemb, eemb, maxlen, outf);
  }
}

// Round 3
// 330.192 us; speedup vs baseline: 1.1835x; 1.1835x over previous
//
#include <hip/hip_runtime.h>
#include <hip/hip_bf16.h>
#include <stdint.h>

// ---------------------------------------------------------------------------
// VarianceAdaptor. Round 6: revert round-5 LDS-fusion (killed 2-block/CU
// overlap, +2.4M bank conflicts). Back to round-4 two-dispatch structure,
// now with a counted-vmcnt deep pipeline in k_conv: 3 LDS buffers, 2 tiles
// in flight, s_waitcnt vmcnt(6) + raw s_barrier per K-step (never drains
// vmcnt to 0 in the main loop — AITER/T4 pattern), setprio(1) around the
// MFMA cluster. LDS 76.8KB -> still 2 blocks/CU.
// Conv core: block tile 128x256, 4 waves, wave 64x128 (4x8 MFMA 16x16x32
// bf16), global_load_lds width=16 with source-side XOR swizzle.
// LR merged into conv dispatches (backfills tail); k_lr fallback kept.
// ---------------------------------------------------------------------------

typedef __bf16 bf16;
typedef __attribute__((ext_vector_type(8))) __bf16 bf16x8;
typedef __attribute__((ext_vector_type(4))) float f32x4;

#define TSEQ 1024

// output chunk offsets (floats)
#define O1 33554432          // pitch_pred
#define O2 33587200          // energy_pred
#define O3 33619968          // log_dur
#define O4 33652736          // duration passthrough
#define O5 33685504          // mel_len
#define O6 33685536          // mel_mask

// end of real outputs in d_out (bytes): (O6 + 131072) * 4
#define OUT_END_B 135266432

// legacy d_out scratch byte offsets (fallback path only)
#define XB_OFF 512
#define H1B_OFF (XB_OFF + 16777216)
#define H1B_SZ 16777216
#define WT_OFF (H1B_OFF + 3 * H1B_SZ)
#define WT_SZ 393216

// scratch region sizes
#define XB_SZ 16777216
#define H1B_TOT (3 * H1B_SZ)
#define WT_TOT (6 * WT_SZ)
#define SCRATCH_SZ (XB_SZ + H1B_TOT + WT_TOT)

// ws byte offsets
#define CUM_OFF 0
#define ADDROW_OFF 131072
#define ZEROS_OFF 262144
#define WS_SCR_OFF 524288
#define WS_NEED ((size_t)WS_SCR_OFF + (size_t)SCRATCH_SZ)

// ---------------------------------------------------------------------------
// Fused prep: [0,4096) cvt_x | [4096,4672) cvt_w | [4672,4800) bins+zpage |
// [4800,4832) scan. All independent; consumed by later dispatches.
__global__ __launch_bounds__(256) void k_prep(
    const float* __restrict__ x, bf16* __restrict__ xb,
    const float* __restrict__ w1, const float* __restrict__ w2,
    bf16* __restrict__ wt,
    const float* __restrict__ pt, const float* __restrict__ et,
    const float* __restrict__ pbins, const float* __restrict__ ebins,
    int* __restrict__ addrow, float* __restrict__ zpage,
    const int* __restrict__ dur, const int* __restrict__ maxlen,
    float* __restrict__ out, int* __restrict__ cum) {
  int bid = blockIdx.x;
  int tid = threadIdx.x;
  if (bid < 4096) {
    // fp32 -> bf16 copy of x (plain row-major, 256 ch/row)
    int t = bid * 256 + tid;
    int g = t >> 5;
    int u = t & 31;
    const float4* s = (const float4*)(x + ((size_t)g << 8) + (u << 3));
    float4 a = s[0], b = s[1];
    bf16x8 o;
    o[0] = (bf16)a.x; o[1] = (bf16)a.y; o[2] = (bf16)a.z; o[3] = (bf16)a.w;
    o[4] = (bf16)b.x; o[5] = (bf16)b.y; o[6] = (bf16)b.z; o[7] = (bf16)b.w;
    *(bf16x8*)(xb + ((size_t)g << 8) + (u << 3)) = o;
  } else if (bid < 4672) {
    // (3,K,H,F) WIO fp32 -> wT[m][f][k] bf16 (k = dt*256 + c)
    int bw = bid - 4096;
    int m = bw / 96;
    int r = bw % 96;
    int f = (r & 3) * 64 + (tid & 63);
    int u = (r >> 2) * 4 + (tid >> 6);
    const float* W = (m < 3) ? w1 : w2;
    int i = (m < 3) ? m : m - 3;
    int dt = u >> 5;
    int c0 = (u & 31) << 3;
    const float* src = W + (((size_t)(i * 3 + dt) * 256 + c0) << 8) + f;
    bf16x8 o;
#pragma unroll
    for (int cc = 0; cc < 8; ++cc) o[cc] = (bf16)src[(size_t)cc << 8];
    *(bf16x8*)(wt + (size_t)m * 196608 + (size_t)f * 768 + (u << 3)) = o;
  } else if (bid < 4800) {
    // searchsorted(left) of pitch/energy targets into bins; zero the zpage
    __shared__ float pb[255], eb[255];
    if (tid < 255) { pb[tid] = pbins[tid]; eb[tid] = ebins[tid]; }
    if (bid == 4672 && tid < 64) zpage[tid] = 0.f;
    __syncthreads();
    int g = (bid - 4672) * 256 + tid;
    float pv = pt[g], ev = et[g];
    int lo = 0, hi = 255;
    while (lo < hi) { int md = (lo + hi) >> 1; if (pb[md] < pv) lo = md + 1; else hi = md; }
    int pi = lo;
    lo = 0; hi = 255;
    while (lo < hi) { int md = (lo + hi) >> 1; if (eb[md] < ev) lo = md + 1; else hi = md; }
    addrow[g] = pi | (lo << 16);
  } else {
    // cumsum(dur) + mel_len + duration passthrough
    __shared__ int lds[256];
    int b = bid - 4800;
    int4 d = ((const int4*)(dur + b * 1024))[tid];
    int p0 = d.x, p1 = p0 + d.y, p2 = p1 + d.z, p3 = p2 + d.w;
    int val = p3;
    lds[tid] = val;
    __syncthreads();
    for (int off = 1; off < 256; off <<= 1) {
      int t = (tid >= off) ? lds[tid - off] : 0;
      __syncthreads();
      val += t;
      lds[tid] = val;
      __syncthreads();
    }
    int excl = val - p3;
    int4 c;
    c.x = excl + p0; c.y = excl + p1; c.z = excl + p2; c.w = excl + p3;
    ((int4*)(cum + b * 1024))[tid] = c;
    float4 fd;
    fd.x = (float)d.x; fd.y = (float)d.y; fd.z = (float)d.z; fd.w = (float)d.w;
    ((float4*)(out + O4 + b * 1024))[tid] = fd;
    if (tid == 255) {
      int mel = val < maxlen[0] ? val : maxlen[0];
      out[O5 + b] = (float)mel;
    }
  }
}

// ---------------------------------------------------------------------------
// Fused conv(k=3) GEMM + bias + ReLU + LN (+ linear head for mode=1),
// PLUS length-regulator role for blocks >= 768 (backfills the conv tail).
// Conv: blocks [0,768): y = bid>>8, 4 waves; wave (rh,ch) computes rows
// rh*64+[0,64) x cols ch*128+[0,128). 3-buffer LDS pipeline, 2 tiles in
// flight, counted s_waitcnt vmcnt(6) (drains to 0 only on the last tile).
__global__ __launch_bounds__(256, 2) void k_conv(
    const char* __restrict__ Ab, size_t AperY, const char* __restrict__ Wb,
    const float* __restrict__ bias0, const float* __restrict__ gamma0,
    const float* __restrict__ beta0, char* __restrict__ hout0,
    const float* __restrict__ lw0, const float* __restrict__ lb0,
    const unsigned char* __restrict__ mask, float* __restrict__ outb,
    const char* __restrict__ zpage, int mode,
    const float* __restrict__ xf, const int* __restrict__ cum,
    const int* __restrict__ addrow, const float* __restrict__ pemb,
    const float* __restrict__ eemb, const int* __restrict__ maxlen,
    int lrbase) {
  __shared__ __align__(16) char Abuf[3][8192];    // 128 rows x 64B, 3-buf
  __shared__ __align__(16) char Bbuf[3][16384];   // 256 f x 64B, 3-buf
  __shared__ float redS[128][2];
  __shared__ float redS2[128][2];
  __shared__ float predr[128][2];

  const int tid = threadIdx.x;
  const int bid = blockIdx.x;

  if (bid >= 768) {
    // ---- length-regulator role (memory-bound; fills conv tail) ----
    int* cl = (int*)Abuf;                    // reuse 4KB of Abuf
    int rid0 = lrbase + ((bid - 768) << 4);  // 16 rows per block
    int b = rid0 >> 12;
    ((int4*)cl)[tid] = ((const int4*)(cum + (b << 10)))[tid];
    __syncthreads();
    int lane = tid & 63;
    int wv = tid >> 6;
    int total = cl[1023];
    int ml = maxlen[0];
    int mel = total < ml ? total : ml;
    int c1 = cl[lane * 16 + 15];             // segment maxima, level-1 search
#pragma unroll
    for (int rr = 0; rr < 4; ++rr) {
      int rid = rid0 + (wv << 2) + rr;
      int j = rid & 4095;
      bool valid = j < mel;
      float4 res = {0.f, 0.f, 0.f, 0.f};
      if (valid) {
        unsigned long long m1 = __ballot(j < c1);
        int s = __ffsll(m1) - 1;
        unsigned long long m2 = __ballot(j < cl[s * 16 + (lane & 15)]);
        int p = __ffsll(m2) - 1;
        int i = s * 16 + p;
        int ar = addrow[(b << 10) + i];
        int pi = ar & 0xffff, ei = ar >> 16;
        const float4* xr = (const float4*)(xf + (((size_t)(b << 10) + i) << 8));
        const float4* pr = (const float4*)(pemb + ((size_t)pi << 8));
        const float4* er = (const float4*)(eemb + ((size_t)ei << 8));
        float4 a = xr[lane], pp = pr[lane], e = er[lane];
        res.x = a.x + pp.x + e.x;
        res.y = a.y + pp.y + e.y;
        res.z = a.z + pp.z + e.z;
        res.w = a.w + pp.w + e.w;
      }
      ((float4*)(outb + ((size_t)rid << 8)))[lane] = res;
      if (lane == 0) outb[O6 + rid] = valid ? 0.f : 1.f;
    }
    return;
  }

  const int wv = tid >> 6;
  const int ln = tid & 63;
  const int q = ln >> 4;
  const int m16 = ln & 15;
  const int rh = wv >> 1;
  const int ch = wv & 1;
  const int y = bid >> 8;
  const int g0 = (bid & 255) << 7;
  const int t0 = g0 & (TSEQ - 1);

  const char* A = Ab + (size_t)y * AperY;
  const char* W = Wb + (size_t)y * WT_SZ;

  // staging lane geometry: thread covers (row = j*64 + wv*16 + srow, slot)
  const int srow = ln >> 2;
  const int slot = ln & 3;
  const int usw = slot ^ ((ln >> 3) & 3);   // source-side XOR swizzle

  // B source base per staging instruction j (f = j*64 + wv*16 + srow)
  const char* bsrc[4];
#pragma unroll
  for (int j = 0; j < 4; ++j) {
    int f = j * 64 + wv * 16 + srow;
    bsrc[j] = W + ((size_t)f * 768 + usw * 8) * 2;
  }
  const int rbase = wv * 16 + srow;   // A staging row base (j adds 64)

  f32x4 acc[4][8];
#pragma unroll
  for (int a = 0; a < 4; a++)
#pragma unroll
    for (int b = 0; b < 8; b++) acc[a][b] = (f32x4){0.f, 0.f, 0.f, 0.f};

#define STAGE(KB, BUF)                                                         \
  {                                                                            \
    int dt0_ = (KB) >> 3;                                                      \
    int c0_ = ((KB) & 7) << 5;                                                 \
    char* ad_ = Abuf[BUF];                                                     \
    char* bd_ = Bbuf[BUF];                                                     \
    _Pragma("unroll") for (int j = 0; j < 2; ++j) {                            \
      int rr = j * 64 + rbase + dt0_ - 1;                                      \
      const char* src = ((unsigned)(t0 + rr) < 1024u)                          \
          ? A + (((size_t)(g0 + rr) << 8) + c0_ + usw * 8) * 2                 \
          : zpage + slot * 16;                                                 \
      __builtin_amdgcn_global_load_lds(                                        \
          (const __attribute__((address_space(1))) void*)src,                  \
          (__attribute__((address_space(3))) void*)(ad_ + j * 4096 +           \
                                                    tid * 16),                 \
          16, 0, 0);                                                           \
    }                                                                          \
    _Pragma("unroll") for (int j = 0; j < 4; ++j) {                            \
      __builtin_amdgcn_global_load_lds(                                        \
          (const __attribute__((address_space(1))) void*)(bsrc[j] + (KB)*64),  \
          (__attribute__((address_space(3))) void*)(bd_ + j * 4096 +           \
                                                    tid * 16),                 \
          16, 0, 0);                                                           \
    }                                                                          \
  }

  const int spq = (q ^ ((m16 >> 1) & 3)) << 4;   // fragment slot bytes
  const int aoff = (rh * 64 + m16) * 64 + spq;
  const int boff = (ch * 128 + m16) * 64 + spq;

  // ---- deep pipeline: tiles kb and kb+1 in flight; wait only for kb ----
  STAGE(0, 0);
  STAGE(1, 1);
  int cur = 0, stg = 2;
  for (int kb = 0; kb < 24; ++kb) {
    if (kb < 23)
      asm volatile("s_waitcnt vmcnt(6)" ::: "memory");   // tile kb resident
    else
      asm volatile("s_waitcnt vmcnt(0)" ::: "memory");
    __builtin_amdgcn_s_barrier();
    if (kb < 22) STAGE(kb + 2, stg);                     // 2-deep prefetch
    const char* Ac = Abuf[cur];
    const char* Bc = Bbuf[cur];
    bf16x8 af[4], bfr[8];
#pragma unroll
    for (int mi = 0; mi < 4; ++mi)
      af[mi] = *(const bf16x8*)(Ac + aoff + mi * 1024);
#pragma unroll
    for (int ni = 0; ni < 8; ++ni)
      bfr[ni] = *(const bf16x8*)(Bc + boff + ni * 1024);
    __builtin_amdgcn_s_setprio(1);
#pragma unroll
    for (int mi = 0; mi < 4; ++mi)
#pragma unroll
      for (int ni = 0; ni < 8; ++ni)
        acc[mi][ni] = __builtin_amdgcn_mfma_f32_16x16x32_bf16(
            af[mi], bfr[ni], acc[mi][ni], 0, 0, 0);
    __builtin_amdgcn_s_setprio(0);
    // all frag reads done before any wave re-stages this buffer (2 barriers
    // away); drain lgkm so the next barrier is a true read-completion fence
    asm volatile("s_waitcnt lgkmcnt(0)" ::: "memory");
    cur = (cur == 2) ? 0 : cur + 1;
    stg = (stg == 2) ? 0 : stg + 1;
  }
#undef STAGE

  // bias + ReLU + LN stats (row partials per col-half into LDS)
  const float* bias = bias0 + y * 256;
  const float* gamma = gamma0 + y * 256;
  const float* beta = beta0 + y * 256;
  float bias_v[8], g_v[8], be_v[8], lw_v[8];
#pragma unroll
  for (int ni = 0; ni < 8; ni++) {
    int nf = (ch << 7) + (ni << 4) + m16;
    bias_v[ni] = bias[nf];
    g_v[ni] = gamma[nf];
    be_v[ni] = beta[nf];
  }
  if (mode) {
    const float* lw = lw0 + y * 256;
#pragma unroll
    for (int ni = 0; ni < 8; ni++) lw_v[ni] = lw[(ch << 7) + (ni << 4) + m16];
  }

#pragma unroll
  for (int mi = 0; mi < 4; mi++) {
#pragma unroll
    for (int r = 0; r < 4; r++) {
      float s1 = 0.f, s2 = 0.f;
#pragma unroll
      for (int ni = 0; ni < 8; ni++) {
        float v = acc[mi][ni][r] + bias_v[ni];
        v = fmaxf(v, 0.f);
        acc[mi][ni][r] = v;
        s1 += v;
        s2 += v * v;
      }
#pragma unroll
      for (int d = 1; d < 16; d <<= 1) {
        s1 += __shfl_xor(s1, d);
        s2 += __shfl_xor(s2, d);
      }
      if (m16 == 0) {
        int m = (rh << 6) + (mi << 4) + (q << 2) + r;
        redS[m][ch] = s1;
        redS2[m][ch] = s2;
      }
    }
  }
  __syncthreads();

  if (mode == 0) {
    bf16* hp = (bf16*)(hout0 + (size_t)y * H1B_SZ);
#pragma unroll
    for (int mi = 0; mi < 4; mi++) {
#pragma unroll
      for (int r = 0; r < 4; r++) {
        int m = (rh << 6) + (mi << 4) + (q << 2) + r;
        float mu = (redS[m][0] + redS[m][1]) * 0.00390625f;
        float var = (redS2[m][0] + redS2[m][1]) * 0.00390625f - mu * mu;
        float rs = rsqrtf(var + 1e-5f);
        int gg = g0 + m;
#pragma unroll
        for (int ni = 0; ni < 8; ni++) {
          float v = (acc[mi][ni][r] - mu) * rs * g_v[ni] + be_v[ni];
          int n = (ch << 7) + (ni << 4) + m16;
          hp[((size_t)gg << 8) + n] = (bf16)v;
        }
      }
    }
  } else {
#pragma unroll
    for (int mi = 0; mi < 4; mi++) {
#pragma unroll
      for (int r = 0; r < 4; r++) {
        int m = (rh << 6) + (mi << 4) + (q << 2) + r;
        float mu = (redS[m][0] + redS[m][1]) * 0.00390625f;
        float var = (redS2[m][0] + redS2[m][1]) * 0.00390625f - mu * mu;
        float rs = rsqrtf(var + 1e-5f);
        float p = 0.f;
#pragma unroll
        for (int ni = 0; ni < 8; ni++) {
          float v = (acc[mi][ni][r] - mu) * rs * g_v[ni] + be_v[ni];
          p += v * lw_v[ni];
        }
#pragma unroll
        for (int d = 1; d < 16; d <<= 1) p += __shfl_xor(p, d);
        if (m16 == 0) predr[m][ch] = p;
      }
    }
    __syncthreads();
    if (tid < 128) {
      int gg = g0 + tid;
      float p = predr[tid][0] + predr[tid][1] + lb0[y];
      if (mask[gg]) p = 0.f;
      float* pd = outb + (y == 0 ? O3 : (y == 1 ? O1 : O2));
      pd[gg] = p;
    }
  }
}

// ---------------------------------------------------------------------------
// Standalone length regulation (fallback path only). 16 rows/block;
// grid MUST be 8192 to cover all 32*4096 output rows.
__global__ __launch_bounds__(256) void k_lr(const float* __restrict__ x,
                                            const int* __restrict__ cum,
                                            const int* __restrict__ addrow,
                                            const float* __restrict__ pemb,
                                            const float* __restrict__ eemb,
                                            const int* __restrict__ maxlen,
                                            float* __restrict__ outb) {
  __shared__ int cl[1024];
  int tid = threadIdx.x;
  int rid0 = blockIdx.x << 4;          // 16 rows per block
  int b = rid0 >> 12;
  ((int4*)cl)[tid] = ((const int4*)(cum + (b << 10)))[tid];
  __syncthreads();
  int lane = tid & 63;
  int wv = tid >> 6;
  int total = cl[1023];
  int ml = maxlen[0];
  int mel = total < ml ? total : ml;
  int c1 = cl[lane * 16 + 15];         // segment maxima for level-1 search
#pragma unroll
  for (int rr = 0; rr < 4; ++rr) {
    int rid = rid0 + (wv << 2) + rr;
    int j = rid & 4095;
    bool valid = j < mel;
    float4 res = {0.f, 0.f, 0.f, 0.f};
    if (valid) {
      unsigned long long m1 = __ballot(j < c1);
      int s = __ffsll(m1) - 1;
      unsigned long long m2 = __ballot(j < cl[s * 16 + (lane & 15)]);
      int p = __ffsll(m2) - 1;
      int i = s * 16 + p;
      int ar = addrow[(b << 10) + i];
      int pi = ar & 0xffff, ei = ar >> 16;
      const float4* xr = (const float4*)(x + (((size_t)(b << 10) + i) << 8));
      const float4* pr = (const float4*)(pemb + ((size_t)pi << 8));
      const float4* er = (const float4*)(eemb + ((size_t)ei << 8));
      float4 a = xr[lane], pp = pr[lane], e = er[lane];
      res.x = a.x + pp.x + e.x;
      res.y = a.y + pp.y + e.y;
      res.z = a.z + pp.z + e.z;
      res.w = a.w + pp.w + e.w;
    }
    ((float4*)(outb + ((size_t)rid << 8)))[lane] = res;
    if (lane == 0) outb[O6 + rid] = valid ? 0.f : 1.f;
  }
}

// ---------------------------------------------------------------------------
extern "C" void kernel_launch(void* const* d_in, const int* in_sizes, int n_in,
                              void* d_out, int out_size, void* d_ws, size_t ws_size,
                              hipStream_t stream) {
  const float* x = (const float*)d_in[0];
  const unsigned char* src_mask = (const unsigned char*)d_in[1];
  const int* dur = (const int*)d_in[2];
  const float* pt = (const float*)d_in[3];
  const float* et = (const float*)d_in[4];
  const int* maxlen = (const int*)d_in[5];
  const float* w1 = (const float*)d_in[6];
  const float* b1 = (const float*)d_in[7];
  const float* g1 = (const float*)d_in[8];
  const float* be1 = (const float*)d_in[9];
  const float* w2 = (const float*)d_in[10];
  const float* b2 = (const float*)d_in[11];
  const float* g2 = (const float*)d_in[12];
  const float* be2 = (const float*)d_in[13];
  const float* lw = (const float*)d_in[14];
  const float* lb = (const float*)d_in[15];
  const float* pbins = (const float*)d_in[16];
  const float* pemb = (const float*)d_in[17];
  const float* ebins = (const float*)d_in[18];
  const float* eemb = (const float*)d_in[19];

  float* outf = (float*)d_out;
  char* ob = (char*)d_out;
  int* cum = (int*)((char*)d_ws + CUM_OFF);
  int* addrow = (int*)((char*)d_ws + ADDROW_OFF);
  float* zpage = (float*)((char*)d_ws + ZEROS_OFF);

  // Scratch placement: prefer ws, then d_out tail beyond real outputs,
  // else legacy overlapped layout (requires separate final k_lr dispatch).
  int merged = 0;
  char* sb = nullptr;
  if (ws_size >= WS_NEED) {
    sb = (char*)d_ws + WS_SCR_OFF;
    merged = 1;
  } else if ((size_t)out_size >= (size_t)OUT_END_B + (size_t)SCRATCH_SZ) {
    sb = ob + OUT_END_B;
    merged = 1;
  }
  bf16* xb;
  char* h1b;
  bf16* wt;
  if (merged) {
    xb = (bf16*)sb;
    h1b = sb + XB_SZ;
    wt = (bf16*)(sb + XB_SZ + H1B_TOT);
  } else {
    xb = (bf16*)(ob + XB_OFF);
    h1b = ob + H1B_OFF;
    wt = (bf16*)(ob + WT_OFF);
  }

  hipLaunchKernelGGL(k_prep, dim3(4832), dim3(256), 0, stream,
                     x, xb, w1, w2, wt, pt, et, pbins, ebins, addrow, zpage,
                     dur, maxlen, outf, cum);

  // 768 conv blocks (+4096 LR backfill blocks each when merged).
  int gconv = merged ? 768 + 4096 : 768;
  hipLaunchKernelGGL(k_conv, dim3(gconv), dim3(256), 0, stream,
                     (const char*)xb, (size_t)0, (const char*)wt, b1, g1, be1,
                     h1b, lw, lb, src_mask, outf, (const char*)zpage, 0,
                     x, cum, addrow, pemb, eemb, maxlen, 0);
  hipLaunchKernelGGL(k_conv, dim3(gconv), dim3(256), 0, stream,
                     (const char*)h1b, (size_t)H1B_SZ,
                     (const char*)wt + 3 * WT_SZ, b2, g2, be2,
                     (char*)nullptr, lw, lb, src_mask, outf,
                     (const char*)zpage, 1,
                     x, cum, addrow, pemb, eemb, maxlen, 65536);
  if (!merged) {
    hipLaunchKernelGGL(k_lr, dim3(8192), dim3(256), 0, stream, x, cum, addrow,
                       pemb, eemb, maxlen, outf);
  }
}